// Round 5
// baseline (839.801 us; speedup 1.0000x reference)
//
#include <hip/hip_runtime.h>

// NSDE pricer, R5: occupancy 2 waves/SIMD + VALU diet.
// Block = 1 path = 256 thr = 4 waves; each wave = one 16-row M-tile (16 options).
// Grid = 512 -> 2048 waves = 2/SIMD (VGPR cap 256 via __launch_bounds__(256,2)):
// sibling wave hides MFMA-block, shfl-chain and LDS latencies (R4: 32% idle at
// 1 wave/SIMD). W1 resident as bf16 B-frags (128 VGPR). bf16 pack via
// round-half-up + v_perm_b32 (3 ops/pair vs 8); b1 folded into MFMA C-init.

#define N_PATHS 512
#define N_STEPS 32
#define B_OPTS  64
#define HID     64

typedef __attribute__((ext_vector_type(8))) short bf16x8;   // 8 bf16 (4 VGPRs)
typedef __attribute__((ext_vector_type(4))) float f32x4;

__device__ __forceinline__ float fast_tanh(float x) {
    // tanh(x) = 1 - 2/(e^{2x}+1); exp2-based, correct saturation at +/-inf.
    float u = __builtin_amdgcn_exp2f(x * 2.8853900817779268f);
    float r = __builtin_amdgcn_rcpf(u + 1.0f);
    return fmaf(-2.0f, r, 1.0f);
}

// two fp32 -> packed bf16x2 (round-half-up), 2 add + 1 perm.
__device__ __forceinline__ int pack_bf16(float a, float b) {
    union { float f; unsigned u; } ca, cb; ca.f = a; cb.f = b;
    const unsigned ua = ca.u + 0x8000u;
    const unsigned ub = cb.u + 0x8000u;
    return (int)__builtin_amdgcn_perm(ub, ua, 0x07060302u); // [ub.hi16 | ua.hi16]
}

__device__ __forceinline__ float select4(float a0, float a1, float a2, float a3, int idx) {
    float lo = (idx & 1) ? a1 : a0;
    float hi = (idx & 1) ? a3 : a2;
    return (idx & 2) ? hi : lo;
}

// Two nets of one phase for ONE 16-row M-tile.
// fout[nn][reg] = f for local row (4q + reg), valid in all lanes of quad q.
__device__ __forceinline__ void mlp_pair(
    int base, int q, int nh, float Sa, float Va, float tA,
    const float4* __restrict__ w0t4,            // LDS, [4][72] swizzled
    const bf16x8 (&bfr)[4][4][2],
    const float (&b1v)[4][4], const float (&w2v)[4][4], const float (&b2s)[4],
    float (&fout)[2][4])
{
#pragma unroll
    for (int nn = 0; nn < 2; ++nn) {
        const int net = base + nn;
        // ---- layer1 in A-fragment layout: lane holds h1[row=nh][k=32kh+8q+j]
        union { bf16x8 v; int i[4]; } afr[2];   // [kh]
#pragma unroll
        for (int kh = 0; kh < 2; ++kh) {
#pragma unroll
            for (int jp = 0; jp < 4; ++jp) {
                const int k0 = kh * 32 + q * 8 + 2 * jp;
                const float4 wA = w0t4[net * 72 + k0     + (k0 >> 3)];
                const float4 wB = w0t4[net * 72 + k0 + 1 + ((k0 + 1) >> 3)];
                const float a0 = fmaf(Sa, wA.x, fmaf(Va, wA.y, fmaf(tA, wA.z, wA.w)));
                const float a1 = fmaf(Sa, wB.x, fmaf(Va, wB.y, fmaf(tA, wB.z, wB.w)));
                afr[kh].i[jp] = pack_bf16(fast_tanh(a0), fast_tanh(a1));
            }
        }
        // ---- layer2: 4 N-tiles x 2 K-halves; b1 pre-loaded into C
        f32x4 C[4];
#pragma unroll
        for (int nt = 0; nt < 4; ++nt) {
            const float bv = b1v[net][nt];
            f32x4 c = {bv, bv, bv, bv};
            c = __builtin_amdgcn_mfma_f32_16x16x32_bf16(afr[0].v, bfr[net][nt][0], c, 0, 0, 0);
            c = __builtin_amdgcn_mfma_f32_16x16x32_bf16(afr[1].v, bfr[net][nt][1], c, 0, 0, 0);
            C[nt] = c;
        }
        // ---- layer3: tanh, dot with W2 over nt, reduce over 16 C-columns
#pragma unroll
        for (int reg = 0; reg < 4; ++reg) {
            float s = 0.0f;
#pragma unroll
            for (int nt = 0; nt < 4; ++nt)
                s = fmaf(fast_tanh(C[nt][reg]), w2v[net][nt], s);
            s += __shfl_xor(s, 1);
            s += __shfl_xor(s, 2);
            s += __shfl_xor(s, 4);
            s += __shfl_xor(s, 8);
            fout[nn][reg] = s + b2s[net];
        }
    }
}

__global__ __launch_bounds__(256, 2) void nsde_kernel(
    const float* __restrict__ S0p, const float* __restrict__ Kp,
    const float* __restrict__ Tp,  const float* __restrict__ rfp,
    const float* __restrict__ Z1,  const float* __restrict__ Z2,
    const float* __restrict__ W0,  const float* __restrict__ b0,
    const float* __restrict__ W1,  const float* __restrict__ b1,
    const float* __restrict__ W2,  const float* __restrict__ b2,
    float* __restrict__ out, float* __restrict__ ws, int use_ws)
{
    const int tid  = threadIdx.x;
    const int wave = tid >> 6;
    const int lane = tid & 63;
    const int q    = lane >> 4;
    const int nh   = lane & 15;
    const int path = blockIdx.x;                    // block = 1 path

    __shared__ float  S_lds[B_OPTS], V_lds[B_OPTS];
    __shared__ float4 w0t4[4 * 72];                 // swizzled (w_S,w_V,w_t, b0+rf*w_rf)

    const float rf = rfp[0];

    // ---- one-time staging ----
    {
        const int net = tid >> 6, kk = tid & 63;    // 256 threads = 4x64
        const float wsv = W0[net * 256 + 0 * 64 + kk];
        const float wvv = W0[net * 256 + 1 * 64 + kk];
        const float wrv = W0[net * 256 + 2 * 64 + kk];
        const float wtv = W0[net * 256 + 3 * 64 + kk];
        w0t4[net * 72 + kk + (kk >> 3)] =
            make_float4(wsv, wvv, wtv, fmaf(rf, wrv, b0[net * 64 + kk]));
    }
    if (tid < B_OPTS) { S_lds[tid] = S0p[tid]; V_lds[tid] = 0.2f; }

    // ---- per-lane constants ----
    const int lA = wave * 16 + nh;                  // A-layout local row (= option)
    const int lW = wave * 16 + 4 * q + (nh & 3);    // writer local row
    const float dta = Tp[lA] * (1.0f / N_STEPS);
    const float dtw = Tp[lW] * (1.0f / N_STEPS);
    const float sqw = sqrtf(dtw);

    float b1v[4][4], w2v[4][4], b2s[4];
#pragma unroll
    for (int net = 0; net < 4; ++net) {
        b2s[net] = b2[net];
#pragma unroll
        for (int nt = 0; nt < 4; ++nt) {
            b1v[net][nt] = b1[net * 64 + nt * 16 + nh];
            w2v[net][nt] = W2[net * 64 + nt * 16 + nh];
        }
    }

    // ---- W1 -> resident bf16 B-fragments: B[k=32kh+8q+j][n=16nt+nh] ----
    bf16x8 bfr[4][4][2];
#pragma unroll
    for (int net = 0; net < 4; ++net)
#pragma unroll
        for (int nt = 0; nt < 4; ++nt)
#pragma unroll
            for (int kh = 0; kh < 2; ++kh) {
                union { bf16x8 v; int i[4]; } t;
#pragma unroll
                for (int jp = 0; jp < 4; ++jp) {
                    const float w0f = W1[net * 4096 + (kh * 32 + q * 8 + 2 * jp    ) * 64 + nt * 16 + nh];
                    const float w1f = W1[net * 4096 + (kh * 32 + q * 8 + 2 * jp + 1) * 64 + nt * 16 + nh];
                    t.i[jp] = pack_bf16(w0f, w1f);
                }
                bfr[net][nt][kh] = t.v;
            }

    __syncthreads();

    const float* __restrict__ z1p = Z1 + path * N_STEPS;
    const float* __restrict__ z2p = Z2 + path * N_STEPS;

    for (int step = 0; step < N_STEPS; ++step) {
        const float z1 = z1p[step];
        const float z2 = z2p[step];
        const float tA = dta * (float)step;
        const int   r  = nh & 3;

        // ---- phase 1: nets 0,1 on (S, V, rf, t) ----
        float f[2][4];
        mlp_pair(0, q, nh, S_lds[lA], V_lds[lA], tA,
                 w0t4, bfr, b1v, w2v, b2s, f);
        {
            const float fd = select4(f[0][0], f[0][1], f[0][2], f[0][3], r);
            const float fz = select4(f[1][0], f[1][1], f[1][2], f[1][3], r);
            const float Sn = S_lds[lW] * fmaf(fz, z1, fmaf(fd, dtw, 1.0f));
            if (nh < 4) S_lds[lW] = Sn;
        }

        // ---- phase 2: nets 2,3 on (S_new, V, rf, t) ----
        float g[2][4];
        mlp_pair(2, q, nh, S_lds[lA], V_lds[lA], tA,
                 w0t4, bfr, b1v, w2v, b2s, g);
        {
            const float gd = select4(g[0][0], g[0][1], g[0][2], g[0][3], r);
            const float gz = select4(g[1][0], g[1][1], g[1][2], g[1][3], r);
            const float Vn = V_lds[lW] * fmaf(gz, sqw * z2, fmaf(gd, dtw, 1.0f));
            if (nh < 4) V_lds[lW] = Vn;
        }
    }

    // ---- payoff: per-block (per-path) partials ----
    __syncthreads();
    if (tid < B_OPTS) {
        const float Tt   = Tp[tid];
        const float disc = __builtin_amdgcn_exp2f(-rf * Tt * 1.4426950408889634f)
                           * (1.0f / (float)N_PATHS);
        const float Kv = Kp[tid];
        const float s  = S_lds[tid];
        const float p  = (s - Kv < 0.0f) ? 0.0f : s;
        const float v  = disc * p;
        if (use_ws) ws[path * B_OPTS + tid] = v;
        else        atomicAdd(&out[tid], v);
    }
}

__global__ void reduce_kernel(const float* __restrict__ ws, float* __restrict__ out) {
    __shared__ float acc[4][64];
    const int o = threadIdx.x & 63, g = threadIdx.x >> 6;
    float s = 0.0f;
    for (int b = g; b < N_PATHS; b += 4) s += ws[b * 64 + o];
    acc[g][o] = s;
    __syncthreads();
    if (threadIdx.x < 64)
        out[threadIdx.x] = acc[0][threadIdx.x] + acc[1][threadIdx.x]
                         + acc[2][threadIdx.x] + acc[3][threadIdx.x];
}

__global__ void zero_out_kernel(float* __restrict__ out) {
    out[threadIdx.x] = 0.0f;
}

extern "C" void kernel_launch(void* const* d_in, const int* in_sizes, int n_in,
                              void* d_out, int out_size, void* d_ws, size_t ws_size,
                              hipStream_t stream) {
    const float* S0p = (const float*)d_in[0];
    const float* Kp  = (const float*)d_in[1];
    const float* Tp  = (const float*)d_in[2];
    const float* rfp = (const float*)d_in[3];
    const float* Z1  = (const float*)d_in[4];
    const float* Z2  = (const float*)d_in[5];
    const float* W0  = (const float*)d_in[6];
    const float* b0  = (const float*)d_in[7];
    const float* W1  = (const float*)d_in[8];
    const float* b1  = (const float*)d_in[9];
    const float* W2  = (const float*)d_in[10];
    const float* b2  = (const float*)d_in[11];
    float* out = (float*)d_out;
    float* wsf = (float*)d_ws;

    const int use_ws = (ws_size >= (size_t)(N_PATHS * B_OPTS * sizeof(float))) ? 1 : 0;

    if (!use_ws) zero_out_kernel<<<1, B_OPTS, 0, stream>>>(out);
    nsde_kernel<<<N_PATHS, 256, 0, stream>>>(S0p, Kp, Tp, rfp, Z1, Z2,
                                             W0, b0, W1, b1, W2, b2, out, wsf, use_ws);
    if (use_ws) reduce_kernel<<<1, 256, 0, stream>>>(wsf, out);
}

// Round 6
// 812.985 us; speedup vs baseline: 1.0330x; 1.0330x over previous
//
#include <hip/hip_runtime.h>

// NSDE pricer, R6: 2 waves/SIMD + LDS-resident W1 fragments.
// R5 lesson: __launch_bounds__(256,2) halves the VGPR budget and the compiler
// spilled the 128-VGPR register-resident W1 frags (FETCH 2.1 GB of scratch
// re-reads). R6: W1 bf16 B-frags pre-packed ONCE into LDS in exact fragment
// order (32 KB/block, shared by all 4 waves); hot loop does 8 conflict-free
// ds_read_b128 per net. Working set ~100 VGPR -> no spill at 2 waves/SIMD.
// Block = 1 path = 4 waves x 16 options; grid 512 -> 2048 waves = 2/SIMD.

#define N_PATHS 512
#define N_STEPS 32
#define B_OPTS  64
#define HID     64

typedef __attribute__((ext_vector_type(8))) short bf16x8;   // 8 bf16 (4 VGPRs)
typedef __attribute__((ext_vector_type(4))) float f32x4;

__device__ __forceinline__ float fast_tanh(float x) {
    // tanh(x) = 1 - 2/(e^{2x}+1); exp2-based, correct saturation at +/-inf.
    float u = __builtin_amdgcn_exp2f(x * 2.8853900817779268f);
    float r = __builtin_amdgcn_rcpf(u + 1.0f);
    return fmaf(-2.0f, r, 1.0f);
}

// two fp32 -> packed bf16x2 (round-half-up), 2 add + 1 perm.
__device__ __forceinline__ int pack_bf16(float a, float b) {
    union { float f; unsigned u; } ca, cb; ca.f = a; cb.f = b;
    const unsigned ua = ca.u + 0x8000u;
    const unsigned ub = cb.u + 0x8000u;
    return (int)__builtin_amdgcn_perm(ub, ua, 0x07060302u); // [ub.hi16 | ua.hi16]
}

__device__ __forceinline__ float select4(float a0, float a1, float a2, float a3, int idx) {
    float lo = (idx & 1) ? a1 : a0;
    float hi = (idx & 1) ? a3 : a2;
    return (idx & 2) ? hi : lo;
}

union fragU { int4 i4; bf16x8 v; };

// Two nets of one phase for ONE 16-row M-tile.
// fout[nn][reg] = f for local row (4q + reg), uniform across nh within quad q.
__device__ __forceinline__ void mlp_pair(
    int base, int q, int nh, int lane, float Sa, float Va, float tA,
    const float4* __restrict__ w0t4,            // LDS [4][72] swizzled
    const int*    __restrict__ w1f,             // LDS frag words
    const float (&b1v)[4][4], const float (&w2v)[4][4], const float (&b2s)[4],
    float (&fout)[2][4])
{
#pragma unroll
    for (int nn = 0; nn < 2; ++nn) {
        const int net = base + nn;

        // Prefetch the 8 B-fragments for this net (lane-strided 16B, conflict-free;
        // lgkmcnt covered by the layer-1 VALU below).
        fragU bf[2][4];
#pragma unroll
        for (int kh = 0; kh < 2; ++kh)
#pragma unroll
            for (int nt = 0; nt < 4; ++nt)
                bf[kh][nt].i4 = *(const int4*)(
                    w1f + ((((net * 2 + kh) * 4 + nt) * 64 + lane) * 4));

        // ---- layer1 in A-fragment layout: lane holds h1[row=nh][k=32kh+8q+j]
        union { bf16x8 v; int i[4]; } afr[2];   // [kh]
#pragma unroll
        for (int kh = 0; kh < 2; ++kh) {
#pragma unroll
            for (int jp = 0; jp < 4; ++jp) {
                const int k0 = kh * 32 + q * 8 + 2 * jp;
                const float4 wA = w0t4[net * 72 + k0     + (k0 >> 3)];
                const float4 wB = w0t4[net * 72 + k0 + 1 + ((k0 + 1) >> 3)];
                const float a0 = fmaf(Sa, wA.x, fmaf(Va, wA.y, fmaf(tA, wA.z, wA.w)));
                const float a1 = fmaf(Sa, wB.x, fmaf(Va, wB.y, fmaf(tA, wB.z, wB.w)));
                afr[kh].i[jp] = pack_bf16(fast_tanh(a0), fast_tanh(a1));
            }
        }

        // ---- layer2: 4 N-tiles x 2 K-halves; b1 folded into C init
        f32x4 C[4];
#pragma unroll
        for (int nt = 0; nt < 4; ++nt) {
            const float bv = b1v[net][nt];
            f32x4 c = {bv, bv, bv, bv};
            c = __builtin_amdgcn_mfma_f32_16x16x32_bf16(afr[0].v, bf[0][nt].v, c, 0, 0, 0);
            c = __builtin_amdgcn_mfma_f32_16x16x32_bf16(afr[1].v, bf[1][nt].v, c, 0, 0, 0);
            C[nt] = c;
        }

        // ---- layer3: tanh, dot with W2 over nt, reduce over the 16 C-columns
#pragma unroll
        for (int reg = 0; reg < 4; ++reg) {
            float s = 0.0f;
#pragma unroll
            for (int nt = 0; nt < 4; ++nt)
                s = fmaf(fast_tanh(C[nt][reg]), w2v[net][nt], s);
            s += __shfl_xor(s, 1);
            s += __shfl_xor(s, 2);
            s += __shfl_xor(s, 4);
            s += __shfl_xor(s, 8);
            fout[nn][reg] = s + b2s[net];
        }
    }
}

__global__ __launch_bounds__(256, 2) void nsde_kernel(
    const float* __restrict__ S0p, const float* __restrict__ Kp,
    const float* __restrict__ Tp,  const float* __restrict__ rfp,
    const float* __restrict__ Z1,  const float* __restrict__ Z2,
    const float* __restrict__ W0,  const float* __restrict__ b0,
    const float* __restrict__ W1,  const float* __restrict__ b1,
    const float* __restrict__ W2,  const float* __restrict__ b2,
    float* __restrict__ out, float* __restrict__ ws, int use_ws)
{
    const int tid  = threadIdx.x;
    const int wave = tid >> 6;
    const int lane = tid & 63;
    const int q    = lane >> 4;
    const int nh   = lane & 15;
    const int path = blockIdx.x;                    // block = 1 path

    __shared__ float  S_lds[B_OPTS], V_lds[B_OPTS];
    __shared__ float4 w0t4[4 * 72];                 // swizzled (w_S,w_V,w_t, b0+rf*w_rf)
    __shared__ int    w1f[4 * 2 * 4 * 64 * 4];      // 8192 words = 32 KB: B-frags

    const float rf = rfp[0];

    // ---- one-time staging ----
    {   // W0 -> folded/transposed float4 table
        const int net = tid >> 6, kk = tid & 63;    // 256 threads = 4x64
        const float wsv = W0[net * 256 + 0 * 64 + kk];
        const float wvv = W0[net * 256 + 1 * 64 + kk];
        const float wrv = W0[net * 256 + 2 * 64 + kk];
        const float wtv = W0[net * 256 + 3 * 64 + kk];
        w0t4[net * 72 + kk + (kk >> 3)] =
            make_float4(wsv, wvv, wtv, fmaf(rf, wrv, b0[net * 64 + kk]));
    }
    // W1 -> bf16 B-fragment words: word w = [net][kh][nt][lane][jp]
    for (int w = tid; w < 8192; w += 256) {
        const int jp = w & 3;
        const int ln = (w >> 2) & 63;
        const int nt = (w >> 8) & 3;
        const int kh = (w >> 10) & 1;
        const int nt_net = w >> 11;
        const int lq = ln >> 4, lnh = ln & 15;
        const int k0 = kh * 32 + lq * 8 + 2 * jp;
        const int n  = nt * 16 + lnh;
        const float a = W1[nt_net * 4096 + k0 * 64 + n];
        const float b = W1[nt_net * 4096 + (k0 + 1) * 64 + n];
        w1f[w] = pack_bf16(a, b);
    }
    if (tid < B_OPTS) { S_lds[tid] = S0p[tid]; V_lds[tid] = 0.2f; }

    // ---- per-lane constants ----
    const int lA = wave * 16 + nh;                  // A-layout local row (= option)
    const int lW = wave * 16 + 4 * q + (nh & 3);    // writer local row
    const float dta = Tp[lA] * (1.0f / N_STEPS);
    const float dtw = Tp[lW] * (1.0f / N_STEPS);
    const float sqw = sqrtf(dtw);

    float b1v[4][4], w2v[4][4], b2s[4];
#pragma unroll
    for (int net = 0; net < 4; ++net) {
        b2s[net] = b2[net];
#pragma unroll
        for (int nt = 0; nt < 4; ++nt) {
            b1v[net][nt] = b1[net * 64 + nt * 16 + nh];
            w2v[net][nt] = W2[net * 64 + nt * 16 + nh];
        }
    }

    __syncthreads();

    const float* __restrict__ z1p = Z1 + path * N_STEPS;
    const float* __restrict__ z2p = Z2 + path * N_STEPS;

    for (int step = 0; step < N_STEPS; ++step) {
        const float z1 = z1p[step];
        const float z2 = z2p[step];
        const float tA = dta * (float)step;
        const int   r  = nh & 3;

        // ---- phase 1: nets 0,1 on (S, V, rf, t) ----
        float f[2][4];
        mlp_pair(0, q, nh, lane, S_lds[lA], V_lds[lA], tA,
                 w0t4, w1f, b1v, w2v, b2s, f);
        {
            const float fd = select4(f[0][0], f[0][1], f[0][2], f[0][3], r);
            const float fz = select4(f[1][0], f[1][1], f[1][2], f[1][3], r);
            const float Sn = S_lds[lW] * fmaf(fz, z1, fmaf(fd, dtw, 1.0f));
            if (nh < 4) S_lds[lW] = Sn;             // wave-local slice, no barrier
        }

        // ---- phase 2: nets 2,3 on (S_new, V, rf, t) ----
        float g[2][4];
        mlp_pair(2, q, nh, lane, S_lds[lA], V_lds[lA], tA,
                 w0t4, w1f, b1v, w2v, b2s, g);
        {
            const float gd = select4(g[0][0], g[0][1], g[0][2], g[0][3], r);
            const float gz = select4(g[1][0], g[1][1], g[1][2], g[1][3], r);
            const float Vn = V_lds[lW] * fmaf(gz, sqw * z2, fmaf(gd, dtw, 1.0f));
            if (nh < 4) V_lds[lW] = Vn;
        }
    }

    // ---- payoff: per-block (per-path) partials ----
    __syncthreads();
    if (tid < B_OPTS) {
        const float Tt   = Tp[tid];
        const float disc = __builtin_amdgcn_exp2f(-rf * Tt * 1.4426950408889634f)
                           * (1.0f / (float)N_PATHS);
        const float Kv = Kp[tid];
        const float s  = S_lds[tid];
        const float p  = (s - Kv < 0.0f) ? 0.0f : s;
        const float v  = disc * p;
        if (use_ws) ws[path * B_OPTS + tid] = v;
        else        atomicAdd(&out[tid], v);
    }
}

__global__ void reduce_kernel(const float* __restrict__ ws, float* __restrict__ out) {
    __shared__ float acc[4][64];
    const int o = threadIdx.x & 63, g = threadIdx.x >> 6;
    float s = 0.0f;
    for (int b = g; b < N_PATHS; b += 4) s += ws[b * 64 + o];
    acc[g][o] = s;
    __syncthreads();
    if (threadIdx.x < 64)
        out[threadIdx.x] = acc[0][threadIdx.x] + acc[1][threadIdx.x]
                         + acc[2][threadIdx.x] + acc[3][threadIdx.x];
}

__global__ void zero_out_kernel(float* __restrict__ out) {
    out[threadIdx.x] = 0.0f;
}

extern "C" void kernel_launch(void* const* d_in, const int* in_sizes, int n_in,
                              void* d_out, int out_size, void* d_ws, size_t ws_size,
                              hipStream_t stream) {
    const float* S0p = (const float*)d_in[0];
    const float* Kp  = (const float*)d_in[1];
    const float* Tp  = (const float*)d_in[2];
    const float* rfp = (const float*)d_in[3];
    const float* Z1  = (const float*)d_in[4];
    const float* Z2  = (const float*)d_in[5];
    const float* W0  = (const float*)d_in[6];
    const float* b0  = (const float*)d_in[7];
    const float* W1  = (const float*)d_in[8];
    const float* b1  = (const float*)d_in[9];
    const float* W2  = (const float*)d_in[10];
    const float* b2  = (const float*)d_in[11];
    float* out = (float*)d_out;
    float* wsf = (float*)d_ws;

    const int use_ws = (ws_size >= (size_t)(N_PATHS * B_OPTS * sizeof(float))) ? 1 : 0;

    if (!use_ws) zero_out_kernel<<<1, B_OPTS, 0, stream>>>(out);
    nsde_kernel<<<N_PATHS, 256, 0, stream>>>(S0p, Kp, Tp, rfp, Z1, Z2,
                                             W0, b0, W1, b1, W2, b2, out, wsf, use_ws);
    if (use_ws) reduce_kernel<<<1, 256, 0, stream>>>(wsf, out);
}

// Round 7
// 368.121 us; speedup vs baseline: 2.2813x; 2.2085x over previous
//
#include <hip/hip_runtime.h>

// NSDE pricer, R7: R6 structure with __launch_bounds__(256,1).
// R5/R6 post-mortem: __launch_bounds__(256,2) makes the allocator cap at
// exactly 128 arch-VGPRs (gfx950 occupancy quantum) and the ~120-reg live set
// spills -> 2.1 GB of HBM scratch traffic, identical in both rounds, W1
// placement irrelevant. Fix: keep W1 bf16 B-frags in LDS (32 KB/block, R6)
// and use the R4-proven (256,1) bound; natural allocation ~150-220 VGPR <= 256
// lets HW co-schedule 2 blocks/CU = 2 waves/SIMD from actual usage (grid 512).
// Block = 1 path = 4 waves x 16 options.

#define N_PATHS 512
#define N_STEPS 32
#define B_OPTS  64
#define HID     64

typedef __attribute__((ext_vector_type(8))) short bf16x8;   // 8 bf16 (4 VGPRs)
typedef __attribute__((ext_vector_type(4))) float f32x4;

__device__ __forceinline__ float fast_tanh(float x) {
    // tanh(x) = 1 - 2/(e^{2x}+1); exp2-based, correct saturation at +/-inf.
    float u = __builtin_amdgcn_exp2f(x * 2.8853900817779268f);
    float r = __builtin_amdgcn_rcpf(u + 1.0f);
    return fmaf(-2.0f, r, 1.0f);
}

// two fp32 -> packed bf16x2 (round-half-up), 2 add + 1 perm.
__device__ __forceinline__ int pack_bf16(float a, float b) {
    union { float f; unsigned u; } ca, cb; ca.f = a; cb.f = b;
    const unsigned ua = ca.u + 0x8000u;
    const unsigned ub = cb.u + 0x8000u;
    return (int)__builtin_amdgcn_perm(ub, ua, 0x07060302u); // [ub.hi16 | ua.hi16]
}

__device__ __forceinline__ float select4(float a0, float a1, float a2, float a3, int idx) {
    float lo = (idx & 1) ? a1 : a0;
    float hi = (idx & 1) ? a3 : a2;
    return (idx & 2) ? hi : lo;
}

union fragU { int4 i4; bf16x8 v; };

// Two nets of one phase for ONE 16-row M-tile.
// fout[nn][reg] = f for local row (4q + reg), uniform across nh within quad q.
__device__ __forceinline__ void mlp_pair(
    int base, int q, int nh, int lane, float Sa, float Va, float tA,
    const float4* __restrict__ w0t4,            // LDS [4][72] swizzled
    const int*    __restrict__ w1f,             // LDS frag words
    const float (&b1v)[4][4], const float (&w2v)[4][4], const float (&b2s)[4],
    float (&fout)[2][4])
{
#pragma unroll
    for (int nn = 0; nn < 2; ++nn) {
        const int net = base + nn;

        // Prefetch the 8 B-fragments for this net (lane-strided 16B, conflict-free;
        // lgkmcnt covered by the layer-1 VALU below).
        fragU bf[2][4];
#pragma unroll
        for (int kh = 0; kh < 2; ++kh)
#pragma unroll
            for (int nt = 0; nt < 4; ++nt)
                bf[kh][nt].i4 = *(const int4*)(
                    w1f + ((((net * 2 + kh) * 4 + nt) * 64 + lane) * 4));

        // ---- layer1 in A-fragment layout: lane holds h1[row=nh][k=32kh+8q+j]
        union { bf16x8 v; int i[4]; } afr[2];   // [kh]
#pragma unroll
        for (int kh = 0; kh < 2; ++kh) {
#pragma unroll
            for (int jp = 0; jp < 4; ++jp) {
                const int k0 = kh * 32 + q * 8 + 2 * jp;
                const float4 wA = w0t4[net * 72 + k0     + (k0 >> 3)];
                const float4 wB = w0t4[net * 72 + k0 + 1 + ((k0 + 1) >> 3)];
                const float a0 = fmaf(Sa, wA.x, fmaf(Va, wA.y, fmaf(tA, wA.z, wA.w)));
                const float a1 = fmaf(Sa, wB.x, fmaf(Va, wB.y, fmaf(tA, wB.z, wB.w)));
                afr[kh].i[jp] = pack_bf16(fast_tanh(a0), fast_tanh(a1));
            }
        }

        // ---- layer2: 4 N-tiles x 2 K-halves; b1 folded into C init
        f32x4 C[4];
#pragma unroll
        for (int nt = 0; nt < 4; ++nt) {
            const float bv = b1v[net][nt];
            f32x4 c = {bv, bv, bv, bv};
            c = __builtin_amdgcn_mfma_f32_16x16x32_bf16(afr[0].v, bf[0][nt].v, c, 0, 0, 0);
            c = __builtin_amdgcn_mfma_f32_16x16x32_bf16(afr[1].v, bf[1][nt].v, c, 0, 0, 0);
            C[nt] = c;
        }

        // ---- layer3: tanh, dot with W2 over nt, reduce over the 16 C-columns
#pragma unroll
        for (int reg = 0; reg < 4; ++reg) {
            float s = 0.0f;
#pragma unroll
            for (int nt = 0; nt < 4; ++nt)
                s = fmaf(fast_tanh(C[nt][reg]), w2v[net][nt], s);
            s += __shfl_xor(s, 1);
            s += __shfl_xor(s, 2);
            s += __shfl_xor(s, 4);
            s += __shfl_xor(s, 8);
            fout[nn][reg] = s + b2s[net];
        }
    }
}

__global__ __launch_bounds__(256, 1) void nsde_kernel(
    const float* __restrict__ S0p, const float* __restrict__ Kp,
    const float* __restrict__ Tp,  const float* __restrict__ rfp,
    const float* __restrict__ Z1,  const float* __restrict__ Z2,
    const float* __restrict__ W0,  const float* __restrict__ b0,
    const float* __restrict__ W1,  const float* __restrict__ b1,
    const float* __restrict__ W2,  const float* __restrict__ b2,
    float* __restrict__ out, float* __restrict__ ws, int use_ws)
{
    const int tid  = threadIdx.x;
    const int wave = tid >> 6;
    const int lane = tid & 63;
    const int q    = lane >> 4;
    const int nh   = lane & 15;
    const int path = blockIdx.x;                    // block = 1 path

    __shared__ float  S_lds[B_OPTS], V_lds[B_OPTS];
    __shared__ float4 w0t4[4 * 72];                 // swizzled (w_S,w_V,w_t, b0+rf*w_rf)
    __shared__ int    w1f[4 * 2 * 4 * 64 * 4];      // 8192 words = 32 KB: B-frags

    const float rf = rfp[0];

    // ---- one-time staging ----
    {   // W0 -> folded/transposed float4 table
        const int net = tid >> 6, kk = tid & 63;    // 256 threads = 4x64
        const float wsv = W0[net * 256 + 0 * 64 + kk];
        const float wvv = W0[net * 256 + 1 * 64 + kk];
        const float wrv = W0[net * 256 + 2 * 64 + kk];
        const float wtv = W0[net * 256 + 3 * 64 + kk];
        w0t4[net * 72 + kk + (kk >> 3)] =
            make_float4(wsv, wvv, wtv, fmaf(rf, wrv, b0[net * 64 + kk]));
    }
    // W1 -> bf16 B-fragment words: word w = [net][kh][nt][lane][jp]
    for (int w = tid; w < 8192; w += 256) {
        const int jp = w & 3;
        const int ln = (w >> 2) & 63;
        const int nt = (w >> 8) & 3;
        const int kh = (w >> 10) & 1;
        const int nt_net = w >> 11;
        const int lq = ln >> 4, lnh = ln & 15;
        const int k0 = kh * 32 + lq * 8 + 2 * jp;
        const int n  = nt * 16 + lnh;
        const float a = W1[nt_net * 4096 + k0 * 64 + n];
        const float b = W1[nt_net * 4096 + (k0 + 1) * 64 + n];
        w1f[w] = pack_bf16(a, b);
    }
    if (tid < B_OPTS) { S_lds[tid] = S0p[tid]; V_lds[tid] = 0.2f; }

    // ---- per-lane constants ----
    const int lA = wave * 16 + nh;                  // A-layout local row (= option)
    const int lW = wave * 16 + 4 * q + (nh & 3);    // writer local row
    const float dta = Tp[lA] * (1.0f / N_STEPS);
    const float dtw = Tp[lW] * (1.0f / N_STEPS);
    const float sqw = sqrtf(dtw);

    float b1v[4][4], w2v[4][4], b2s[4];
#pragma unroll
    for (int net = 0; net < 4; ++net) {
        b2s[net] = b2[net];
#pragma unroll
        for (int nt = 0; nt < 4; ++nt) {
            b1v[net][nt] = b1[net * 64 + nt * 16 + nh];
            w2v[net][nt] = W2[net * 64 + nt * 16 + nh];
        }
    }

    __syncthreads();

    const float* __restrict__ z1p = Z1 + path * N_STEPS;
    const float* __restrict__ z2p = Z2 + path * N_STEPS;

    for (int step = 0; step < N_STEPS; ++step) {
        const float z1 = z1p[step];
        const float z2 = z2p[step];
        const float tA = dta * (float)step;
        const int   r  = nh & 3;

        // ---- phase 1: nets 0,1 on (S, V, rf, t) ----
        float f[2][4];
        mlp_pair(0, q, nh, lane, S_lds[lA], V_lds[lA], tA,
                 w0t4, w1f, b1v, w2v, b2s, f);
        {
            const float fd = select4(f[0][0], f[0][1], f[0][2], f[0][3], r);
            const float fz = select4(f[1][0], f[1][1], f[1][2], f[1][3], r);
            const float Sn = S_lds[lW] * fmaf(fz, z1, fmaf(fd, dtw, 1.0f));
            if (nh < 4) S_lds[lW] = Sn;             // wave-local slice, no barrier
        }

        // ---- phase 2: nets 2,3 on (S_new, V, rf, t) ----
        float g[2][4];
        mlp_pair(2, q, nh, lane, S_lds[lA], V_lds[lA], tA,
                 w0t4, w1f, b1v, w2v, b2s, g);
        {
            const float gd = select4(g[0][0], g[0][1], g[0][2], g[0][3], r);
            const float gz = select4(g[1][0], g[1][1], g[1][2], g[1][3], r);
            const float Vn = V_lds[lW] * fmaf(gz, sqw * z2, fmaf(gd, dtw, 1.0f));
            if (nh < 4) V_lds[lW] = Vn;
        }
    }

    // ---- payoff: per-block (per-path) partials ----
    __syncthreads();
    if (tid < B_OPTS) {
        const float Tt   = Tp[tid];
        const float disc = __builtin_amdgcn_exp2f(-rf * Tt * 1.4426950408889634f)
                           * (1.0f / (float)N_PATHS);
        const float Kv = Kp[tid];
        const float s  = S_lds[tid];
        const float p  = (s - Kv < 0.0f) ? 0.0f : s;
        const float v  = disc * p;
        if (use_ws) ws[path * B_OPTS + tid] = v;
        else        atomicAdd(&out[tid], v);
    }
}

__global__ void reduce_kernel(const float* __restrict__ ws, float* __restrict__ out) {
    __shared__ float acc[4][64];
    const int o = threadIdx.x & 63, g = threadIdx.x >> 6;
    float s = 0.0f;
    for (int b = g; b < N_PATHS; b += 4) s += ws[b * 64 + o];
    acc[g][o] = s;
    __syncthreads();
    if (threadIdx.x < 64)
        out[threadIdx.x] = acc[0][threadIdx.x] + acc[1][threadIdx.x]
                         + acc[2][threadIdx.x] + acc[3][threadIdx.x];
}

__global__ void zero_out_kernel(float* __restrict__ out) {
    out[threadIdx.x] = 0.0f;
}

extern "C" void kernel_launch(void* const* d_in, const int* in_sizes, int n_in,
                              void* d_out, int out_size, void* d_ws, size_t ws_size,
                              hipStream_t stream) {
    const float* S0p = (const float*)d_in[0];
    const float* Kp  = (const float*)d_in[1];
    const float* Tp  = (const float*)d_in[2];
    const float* rfp = (const float*)d_in[3];
    const float* Z1  = (const float*)d_in[4];
    const float* Z2  = (const float*)d_in[5];
    const float* W0  = (const float*)d_in[6];
    const float* b0  = (const float*)d_in[7];
    const float* W1  = (const float*)d_in[8];
    const float* b1  = (const float*)d_in[9];
    const float* W2  = (const float*)d_in[10];
    const float* b2  = (const float*)d_in[11];
    float* out = (float*)d_out;
    float* wsf = (float*)d_ws;

    const int use_ws = (ws_size >= (size_t)(N_PATHS * B_OPTS * sizeof(float))) ? 1 : 0;

    if (!use_ws) zero_out_kernel<<<1, B_OPTS, 0, stream>>>(out);
    nsde_kernel<<<N_PATHS, 256, 0, stream>>>(S0p, Kp, Tp, rfp, Z1, Z2,
                                             W0, b0, W1, b1, W2, b2, out, wsf, use_ws);
    if (use_ws) reduce_kernel<<<1, 256, 0, stream>>>(wsf, out);
}